// Round 8
// baseline (583.780 us; speedup 1.0000x reference)
//
#include <hip/hip_runtime.h>
#include <stdint.h>

#define BQ 4
#define NQ 2048
#define DQ 512
#define YQ 8921
#define YGRP 140                 // y-groups of 64
#define NH 4                     // n quarters (512 rows each)
#define NTIL 32                  // 16-row tiles per quarter
#define NUNITS (YGRP * BQ * NH)  // 2240 = 8*280
#define NLP 140
#define L2E 1.44269504088896340736f

typedef __attribute__((ext_vector_type(8))) short bf16x8;
typedef __attribute__((ext_vector_type(4))) float f32x4;

__device__ inline short f2bf(float f) {
  unsigned u = __float_as_uint(f);
  u += 0x7fffu + ((u >> 16) & 1u);   // RTNE
  return (short)(u >> 16);
}

__device__ inline bf16x8 pack8(float4 a, float4 b) {
  bf16x8 h;
  h[0] = f2bf(a.x); h[1] = f2bf(a.y); h[2] = f2bf(a.z); h[3] = f2bf(a.w);
  h[4] = f2bf(b.x); h[5] = f2bf(b.y); h[6] = f2bf(b.z); h[7] = f2bf(b.w);
  return h;
}

// ---- prep: gx[b,n] = x[b,n,:].gate_w ----
__global__ __launch_bounds__(256) void prep_gx(const float* __restrict__ x,
                                               const float* __restrict__ gate_w,
                                               float* __restrict__ gx) {
  int rid = blockIdx.x * 4 + (threadIdx.x >> 6);
  int lane = threadIdx.x & 63;
  const float* src = x + (size_t)rid * DQ + lane * 8;
  float4 v0 = *(const float4*)src;
  float4 v1 = *(const float4*)(src + 4);
  const float* gwp = gate_w + lane * 8;
  float s = v0.x * gwp[0] + v0.y * gwp[1] + v0.z * gwp[2] + v0.w * gwp[3]
          + v1.x * gwp[4] + v1.y * gwp[5] + v1.z * gwp[6] + v1.w * gwp[7];
#pragma unroll
  for (int d = 1; d < 64; d <<= 1) s += __shfl_xor(s, d);
  if (lane == 0) gx[rid] = s;
}

// ---- prep: x -> bf16 MFMA-frag order: [tile16n][kk][lane]*16B (16KB/tile) ----
__global__ __launch_bounds__(256) void prep_xfrag(const float* __restrict__ x,
                                                  char* __restrict__ ws_x2) {
  __shared__ float xs[16 * 512];
  int t = blockIdx.x;                       // b*128 + nt
  const float* src = x + ((size_t)t << 13);
  int tid = threadIdx.x;
#pragma unroll
  for (int i = 0; i < 8; ++i)
    *(float4*)(xs + i * 1024 + tid * 4) = *(const float4*)(src + i * 1024 + tid * 4);
  __syncthreads();
  char* dst = ws_x2 + ((size_t)t << 14);
#pragma unroll
  for (int i = 0; i < 4; ++i) {
    int s = i * 256 + tid;
    int l = s & 63, kk = s >> 6;
    int row = l & 15, g = l >> 4;
    const float* p = xs + row * 512 + kk * 32 + g * 8;
    *(bf16x8*)(dst + s * 16) = pack8(*(const float4*)p, *(const float4*)(p + 4));
  }
}

// ---- prep: W (U,Ug,F) f32 -> bf16 row-major [3][YQ][512] ----
__global__ __launch_bounds__(256) void prep_w(const float* __restrict__ Uw,
                                              const float* __restrict__ Gw,
                                              const float* __restrict__ Fw,
                                              char* __restrict__ ws_w) {
  int rid = blockIdx.x * 4 + (threadIdx.x >> 6);
  if (rid >= 3 * YQ) return;
  int lane = threadIdx.x & 63;
  int mat = rid / YQ, y = rid % YQ;
  const float* src = (mat == 0 ? Uw : (mat == 1 ? Gw : Fw)) + (size_t)y * DQ + lane * 8;
  *(bf16x8*)(ws_w + (size_t)rid * 1024 + lane * 16) =
      pack8(*(const float4*)src, *(const float4*)(src + 4));
}

// ---- fused partial: barrier-free per-wave dataflow, A-frags L2->reg dbuf ----
// unit = (b, yg, nh), nh innermost. 4 waves/block, 1 wave/SIMD (heavy regs).
// Even/odd score sets defer the exp-tail under the next tile's MFMAs.
template<bool FULL>
__global__ __launch_bounds__(256, 1) void fused_kernel(
    const float* __restrict__ x, const char* __restrict__ ws_x2,
    const char* __restrict__ ws_w,
    const float* __restrict__ Uw, const float* __restrict__ Gw,
    const float* __restrict__ Fw, const float* __restrict__ gx,
    float4* __restrict__ ws_state) {
  extern __shared__ char smem[];
  const int tid = threadIdx.x, l = tid & 63, w = tid >> 6;
  const int lr = l & 15, lg4 = l >> 4;
  int u = (blockIdx.x & 7) * (NUNITS / 8) + (blockIdx.x >> 3);
  const int b = u / (YGRP * NH);
  const int r0 = u % (YGRP * NH);
  const int yg = r0 / NH, nh = r0 % NH;
  const int ybase = yg * 64 + w * 16;
  const int nbase = nh * (NQ / NH);

  // ---- W fragments into registers/AGPRs (48 frags) ----
  bf16x8 wU[16], wG[16], wF[16];
  {
    int y = ybase + lr; if (y >= YQ) y = YQ - 1;
    if constexpr (FULL) {
      const char* p0 = ws_w + ((size_t)y * DQ + lg4 * 8) * 2;
#pragma unroll
      for (int kk = 0; kk < 16; ++kk) {
        wU[kk] = *(const bf16x8*)(p0 + kk * 64);
        wG[kk] = *(const bf16x8*)(p0 + (size_t)YQ * 1024 + kk * 64);
        wF[kk] = *(const bf16x8*)(p0 + (size_t)YQ * 2048 + kk * 64);
      }
    } else {
      const float* pu = Uw + (size_t)y * DQ + lg4 * 8;
      const float* pg = Gw + (size_t)y * DQ + lg4 * 8;
      const float* pf = Fw + (size_t)y * DQ + lg4 * 8;
#pragma unroll
      for (int kk = 0; kk < 16; ++kk) {
        wU[kk] = pack8(*(const float4*)(pu + kk * 32), *(const float4*)(pu + kk * 32 + 4));
        wG[kk] = pack8(*(const float4*)(pg + kk * 32), *(const float4*)(pg + kk * 32 + 4));
        wF[kk] = pack8(*(const float4*)(pf + kk * 32), *(const float4*)(pf + kk * 32 + 4));
      }
    }
  }

  float lU = 0.f, aU = 0.f, lG = 0.f, aG = 0.f;

  if constexpr (FULL) {
    // gx quarter into LDS once (512 floats)
    *(float2*)(smem + tid * 8) = *(const float2*)(gx + b * NQ + nbase + tid * 2);
    __syncthreads();

    const char* xb = ws_x2 + (((size_t)(b * 128 + nh * 32)) << 14) + l * 16;
    bf16x8 bA[16], bB[16];
#pragma unroll
    for (int kk = 0; kk < 16; ++kk) bA[kk] = *(const bf16x8*)(xb + kk * 1024);

    f32x4 eU, eG, eF;                       // even-tile scores
    f32x4 oU, oG, oF;                       // odd-tile scores
#pragma unroll
    for (int r = 0; r < 4; ++r) { oU[r] = -1e30f; oG[r] = -1e30f; oF[r] = 0.f; }

#pragma unroll 1
    for (int si = 0; si < 4; ++si) {
#pragma unroll
      for (int pi = 0; pi < 4; ++pi) {
        const int p = si * 4 + pi;          // 0..15
        const int tE = 2 * p, tO = 2 * p + 1;
        // prefetch odd tile -> bB
        {
          const char* src = xb + ((size_t)tO << 14);
#pragma unroll
          for (int kk = 0; kk < 16; ++kk) bB[kk] = *(const bf16x8*)(src + kk * 1024);
        }
        // compute even tile from bA
#pragma unroll
        for (int r = 0; r < 4; ++r) { eU[r] = 0.f; eG[r] = 0.f; eF[r] = 0.f; }
#pragma unroll
        for (int kk = 0; kk < 16; ++kk) {
          eU = __builtin_amdgcn_mfma_f32_16x16x32_bf16(bA[kk], wU[kk], eU, 0, 0, 0);
          eG = __builtin_amdgcn_mfma_f32_16x16x32_bf16(bA[kk], wG[kk], eG, 0, 0, 0);
          eF = __builtin_amdgcn_mfma_f32_16x16x32_bf16(bA[kk], wF[kk], eF, 0, 0, 0);
        }
        // deferred tail: previous ODD tile (tE-1); overlaps even MFMAs above
        {
          const int tp = (tE > 0) ? (tE - 1) : 0;
          float4 gv = *(const float4*)(smem + tp * 64 + lg4 * 16);
          float g4[4] = {gv.x, gv.y, gv.z, gv.w};
#pragma unroll
          for (int r = 0; r < 4; ++r) {
            float eu = __builtin_amdgcn_exp2f(oU[r] * L2E);
            lU += eu; aU = fmaf(eu, oF[r], aU);
            float eg = __builtin_amdgcn_exp2f(oG[r] * L2E);
            lG += eg; aG = fmaf(eg, g4[r], aG);
          }
        }
        // prefetch next even tile -> bA (clamped at the end; junk never used)
        {
          const int tn = (tE + 2 < NTIL) ? (tE + 2) : (NTIL - 1);
          const char* src = xb + ((size_t)tn << 14);
#pragma unroll
          for (int kk = 0; kk < 16; ++kk) bA[kk] = *(const bf16x8*)(src + kk * 1024);
        }
        // compute odd tile from bB
#pragma unroll
        for (int r = 0; r < 4; ++r) { oU[r] = 0.f; oG[r] = 0.f; oF[r] = 0.f; }
#pragma unroll
        for (int kk = 0; kk < 16; ++kk) {
          oU = __builtin_amdgcn_mfma_f32_16x16x32_bf16(bB[kk], wU[kk], oU, 0, 0, 0);
          oG = __builtin_amdgcn_mfma_f32_16x16x32_bf16(bB[kk], wG[kk], oG, 0, 0, 0);
          oF = __builtin_amdgcn_mfma_f32_16x16x32_bf16(bB[kk], wF[kk], oF, 0, 0, 0);
        }
        // deferred tail: even tile tE; overlaps odd MFMAs above
        {
          float4 gv = *(const float4*)(smem + tE * 64 + lg4 * 16);
          float g4[4] = {gv.x, gv.y, gv.z, gv.w};
#pragma unroll
          for (int r = 0; r < 4; ++r) {
            float eu = __builtin_amdgcn_exp2f(eU[r] * L2E);
            lU += eu; aU = fmaf(eu, eF[r], aU);
            float eg = __builtin_amdgcn_exp2f(eG[r] * L2E);
            lG += eg; aG = fmaf(eg, g4[r], aG);
          }
        }
      }
      // drift bound only (no data dependency): keep 4 waves' tile streams
      // close so the shared tiles stay L1-resident.
      __builtin_amdgcn_s_barrier();
    }
    // final tail: odd tile 31
    {
      float4 gv = *(const float4*)(smem + (NTIL - 1) * 64 + lg4 * 16);
      float g4[4] = {gv.x, gv.y, gv.z, gv.w};
#pragma unroll
      for (int r = 0; r < 4; ++r) {
        float eu = __builtin_amdgcn_exp2f(oU[r] * L2E);
        lU += eu; aU = fmaf(eu, oF[r], aU);
        float eg = __builtin_amdgcn_exp2f(oG[r] * L2E);
        lG += eg; aG = fmaf(eg, g4[r], aG);
      }
    }
  } else {
    const float* gxb = gx + b * NQ + nbase + lg4 * 4;
    for (int c = 0; c < NTIL; ++c) {
      __syncthreads();
#pragma unroll
      for (int j = 0; j < 4; ++j) {
        int slot = j * 256 + tid;                  // 1024 slots * 16B = 16KB
        int kk = slot >> 6, l2 = slot & 63;
        int row = l2 & 15, g4i = l2 >> 4;
        const float* g = x + ((size_t)(b * NQ + nbase + c * 16 + row)) * DQ
                       + kk * 32 + g4i * 8;
        *(bf16x8*)(smem + slot * 16) = pack8(*(const float4*)g, *(const float4*)(g + 4));
      }
      __syncthreads();
      const char* ab = smem + l * 16;
      f32x4 sU = {0.f, 0.f, 0.f, 0.f}, sG = sU, sF = sU;
#pragma unroll
      for (int kk = 0; kk < 16; ++kk) {
        bf16x8 a = *(const bf16x8*)(ab + kk * 1024);
        sU = __builtin_amdgcn_mfma_f32_16x16x32_bf16(a, wU[kk], sU, 0, 0, 0);
        sG = __builtin_amdgcn_mfma_f32_16x16x32_bf16(a, wG[kk], sG, 0, 0, 0);
        sF = __builtin_amdgcn_mfma_f32_16x16x32_bf16(a, wF[kk], sF, 0, 0, 0);
      }
      float4 gxv = *(const float4*)(gxb + c * 16);
      float gv[4] = {gxv.x, gxv.y, gxv.z, gxv.w};
#pragma unroll
      for (int r = 0; r < 4; ++r) {
        float eu = __builtin_amdgcn_exp2f(sU[r] * L2E);
        lU += eu; aU = fmaf(eu, sF[r], aU);
        float eg = __builtin_amdgcn_exp2f(sG[r] * L2E);
        lG += eg; aG = fmaf(eg, gv[r], aG);
      }
    }
  }

  // ---- additive lane-group merge ----
#pragma unroll
  for (int d = 16; d < 64; d <<= 1) {
    lU += __shfl_xor(lU, d); aU += __shfl_xor(aU, d);
    lG += __shfl_xor(lG, d); aG += __shfl_xor(aG, d);
  }

  int y = ybase + lr;
  if (lg4 == 0 && y < YQ) {
    float4 st; st.x = lU; st.y = aU; st.z = lG; st.w = aG;
    ws_state[(size_t)(b * NH + nh) * YQ + y] = st;
  }
}

// ---- merge quarters + epilogue + loss partials ----
__global__ __launch_bounds__(256) void merge_kernel(
    const float4* __restrict__ ws_state, const float* __restrict__ fb,
    const float* __restrict__ gate_b, const float* __restrict__ yflow,
    const float* __restrict__ target, float* __restrict__ out_y,
    float* __restrict__ loss_part) {
  __shared__ float sb[256];
  int t = blockIdx.x * 256 + threadIdx.x;
  float lt = 0.f;
  if (t < BQ * YQ) {
    int b = t / YQ, y = t % YQ;
    float lU = 0.f, aU = 0.f, lG = 0.f, aG = 0.f;
#pragma unroll
    for (int nh = 0; nh < NH; ++nh) {
      float4 s = ws_state[(size_t)(b * NH + nh) * YQ + y];
      lU += s.x; aU += s.y; lG += s.z; aG += s.w;
    }
    float gate = tanhf(aG / lG + gate_b[0]);
    float yv = aU / lU + fb[y] + yflow[t] * gate;
    out_y[t] = yv;
    float tg = target[t];
    lt = fmaxf(yv, 0.f) + log1pf(__expf(-fabsf(yv))) - yv * tg;
  }
  sb[threadIdx.x] = lt;
  __syncthreads();
  for (int st = 128; st > 0; st >>= 1) {
    if (threadIdx.x < st) sb[threadIdx.x] += sb[threadIdx.x + st];
    __syncthreads();
  }
  if (threadIdx.x == 0) loss_part[blockIdx.x] = sb[0];
}

__global__ __launch_bounds__(256) void loss_kernel(const float* __restrict__ lp,
                                                   float* __restrict__ out) {
  __shared__ float sb[256];
  float s = (threadIdx.x < NLP) ? lp[threadIdx.x] : 0.f;
  sb[threadIdx.x] = s;
  __syncthreads();
  for (int st = 128; st > 0; st >>= 1) {
    if (threadIdx.x < st) sb[threadIdx.x] += sb[threadIdx.x + st];
    __syncthreads();
  }
  if (threadIdx.x == 0) out[BQ * YQ] = sb[0] / (float)(BQ * YQ);
}

extern "C" void kernel_launch(void* const* d_in, const int* in_sizes, int n_in,
                              void* d_out, int out_size, void* d_ws, size_t ws_size,
                              hipStream_t stream) {
  const float* x      = (const float*)d_in[0];
  const float* target = (const float*)d_in[1];
  const float* yflow  = (const float*)d_in[2];
  const float* Uw     = (const float*)d_in[3];
  const float* Gw     = (const float*)d_in[4];
  const float* Fw     = (const float*)d_in[5];
  const float* fb     = (const float*)d_in[6];
  const float* gw     = (const float*)d_in[7];
  const float* gb     = (const float*)d_in[8];
  float* out = (float*)d_out;
  char* ws = (char*)d_ws;

  const size_t xbytes  = (size_t)BQ * NQ * DQ * 2;          // 8 MB frag-ordered
  const size_t wbytes  = (size_t)3 * YQ * DQ * 2;           // ~27.4 MB
  const size_t gxbytes = (size_t)BQ * NQ * 4;               // 32 KB
  const size_t stbytes = (size_t)BQ * NH * YQ * 16;         // ~2.3 MB
  const size_t lpbytes = (size_t)NLP * 4;
  const bool full = ws_size >= xbytes + wbytes + gxbytes + stbytes + lpbytes;

  char* ws_x2; char* ws_w; float* gxp; float4* stp; float* lp;
  if (full) {
    ws_x2 = ws; ws_w = ws + xbytes;
    gxp = (float*)(ws + xbytes + wbytes);
    stp = (float4*)(ws + xbytes + wbytes + gxbytes);
    lp  = (float*)(ws + xbytes + wbytes + gxbytes + stbytes);
  } else {
    ws_x2 = nullptr; ws_w = nullptr;
    gxp = (float*)ws;
    stp = (float4*)(ws + gxbytes);
    lp  = (float*)(ws + gxbytes + stbytes);
  }

  prep_gx<<<dim3(2048), 256, 0, stream>>>(x, gw, gxp);
  if (full) {
    prep_xfrag<<<dim3(BQ * 128), 256, 0, stream>>>(x, ws_x2);
    prep_w<<<dim3((3 * YQ + 3) / 4), 256, 0, stream>>>(Uw, Gw, Fw, ws_w);
    fused_kernel<true ><<<dim3(NUNITS), 256, 2048, stream>>>(
        x, ws_x2, ws_w, Uw, Gw, Fw, gxp, stp);
  } else {
    fused_kernel<false><<<dim3(NUNITS), 256, 16384, stream>>>(
        x, ws_x2, ws_w, Uw, Gw, Fw, gxp, stp);
  }
  merge_kernel<<<dim3(NLP), 256, 0, stream>>>(stp, fb, gb, yflow, target, out, lp);
  loss_kernel<<<1, 256, 0, stream>>>(lp, out);
}

// Round 9
// 217.551 us; speedup vs baseline: 2.6834x; 2.6834x over previous
//
#include <hip/hip_runtime.h>
#include <stdint.h>

#define BQ 4
#define NQ 2048
#define DQ 512
#define YQ 8921
#define YGRP 140                 // y-groups of 64
#define NH 4                     // n quarters (512 rows each)
#define NCHQ 32                  // chunks per quarter (16 rows each)
#define NUNITS (YGRP * BQ * NH)  // 2240 = 8*280
#define NLP 140
#define GXOFF 65536              // gx area after 4x16KB buffers
#define L2E 1.44269504088896340736f

typedef __attribute__((ext_vector_type(8))) short bf16x8;
typedef __attribute__((ext_vector_type(4))) float f32x4;

__device__ inline short f2bf(float f) {
  unsigned u = __float_as_uint(f);
  u += 0x7fffu + ((u >> 16) & 1u);   // RTNE
  return (short)(u >> 16);
}

__device__ inline bf16x8 pack8(float4 a, float4 b) {
  bf16x8 h;
  h[0] = f2bf(a.x); h[1] = f2bf(a.y); h[2] = f2bf(a.z); h[3] = f2bf(a.w);
  h[4] = f2bf(b.x); h[5] = f2bf(b.y); h[6] = f2bf(b.z); h[7] = f2bf(b.w);
  return h;
}

__device__ inline void gl_lds16(const void* g, void* l) {
  __builtin_amdgcn_global_load_lds((const __attribute__((address_space(1))) void*)g,
                                   (__attribute__((address_space(3))) void*)l, 16, 0, 0);
}

// ---- prep: gx[b,n] = x[b,n,:].gate_w ----
__global__ __launch_bounds__(256) void prep_gx(const float* __restrict__ x,
                                               const float* __restrict__ gate_w,
                                               float* __restrict__ gx) {
  int rid = blockIdx.x * 4 + (threadIdx.x >> 6);
  int lane = threadIdx.x & 63;
  const float* src = x + (size_t)rid * DQ + lane * 8;
  float4 v0 = *(const float4*)src;
  float4 v1 = *(const float4*)(src + 4);
  const float* gwp = gate_w + lane * 8;
  float s = v0.x * gwp[0] + v0.y * gwp[1] + v0.z * gwp[2] + v0.w * gwp[3]
          + v1.x * gwp[4] + v1.y * gwp[5] + v1.z * gwp[6] + v1.w * gwp[7];
#pragma unroll
  for (int d = 1; d < 64; d <<= 1) s += __shfl_xor(s, d);
  if (lane == 0) gx[rid] = s;
}

// ---- prep: x -> bf16 MFMA-frag order: [tile16n][kk][lane]*16B (16KB/tile) ----
__global__ __launch_bounds__(256) void prep_xfrag(const float* __restrict__ x,
                                                  char* __restrict__ ws_x2) {
  __shared__ float xs[16 * 512];
  int t = blockIdx.x;                       // b*128 + nt
  const float* src = x + ((size_t)t << 13);
  int tid = threadIdx.x;
#pragma unroll
  for (int i = 0; i < 8; ++i)
    *(float4*)(xs + i * 1024 + tid * 4) = *(const float4*)(src + i * 1024 + tid * 4);
  __syncthreads();
  char* dst = ws_x2 + ((size_t)t << 14);
#pragma unroll
  for (int i = 0; i < 4; ++i) {
    int s = i * 256 + tid;
    int l = s & 63, kk = s >> 6;
    int row = l & 15, g = l >> 4;
    const float* p = xs + row * 512 + kk * 32 + g * 8;
    *(bf16x8*)(dst + s * 16) = pack8(*(const float4*)p, *(const float4*)(p + 4));
  }
}

// ---- prep: W (U,Ug,F) f32 -> bf16 row-major [3][YQ][512] ----
__global__ __launch_bounds__(256) void prep_w(const float* __restrict__ Uw,
                                              const float* __restrict__ Gw,
                                              const float* __restrict__ Fw,
                                              char* __restrict__ ws_w) {
  int rid = blockIdx.x * 4 + (threadIdx.x >> 6);
  if (rid >= 3 * YQ) return;
  int lane = threadIdx.x & 63;
  int mat = rid / YQ, y = rid % YQ;
  const float* src = (mat == 0 ? Uw : (mat == 1 ? Gw : Fw)) + (size_t)y * DQ + lane * 8;
  *(bf16x8*)(ws_w + (size_t)rid * 1024 + lane * 16) =
      pack8(*(const float4*)src, *(const float4*)(src + 4));
}

// ---- fused partial: paired chunks, 4-deep bufs, barrier every 2 chunks ----
// unit = (b, yg, nh), nh innermost. 4 waves/block, 2 blocks/CU.
template<bool FULL>
__global__ __launch_bounds__(256, 2) void fused_kernel(
    const float* __restrict__ x, const char* __restrict__ ws_x2,
    const char* __restrict__ ws_w,
    const float* __restrict__ Uw, const float* __restrict__ Gw,
    const float* __restrict__ Fw, const float* __restrict__ gx,
    float4* __restrict__ ws_state) {
  extern __shared__ char smem[];
  const int tid = threadIdx.x, l = tid & 63, w = tid >> 6;
  const int lr = l & 15, lg4 = l >> 4;
  int u = (blockIdx.x & 7) * (NUNITS / 8) + (blockIdx.x >> 3);
  const int b = u / (YGRP * NH);
  const int r0 = u % (YGRP * NH);
  const int yg = r0 / NH, nh = r0 % NH;
  const int ybase = yg * 64 + w * 16;
  const int nbase = nh * (NQ / NH);

  // ---- W fragments into registers (48 frags -> AGPRs) ----
  bf16x8 wU[16], wG[16], wF[16];
  {
    int y = ybase + lr; if (y >= YQ) y = YQ - 1;
    if constexpr (FULL) {
      const char* p0 = ws_w + ((size_t)y * DQ + lg4 * 8) * 2;
#pragma unroll
      for (int kk = 0; kk < 16; ++kk) {
        wU[kk] = *(const bf16x8*)(p0 + kk * 64);
        wG[kk] = *(const bf16x8*)(p0 + (size_t)YQ * 1024 + kk * 64);
        wF[kk] = *(const bf16x8*)(p0 + (size_t)YQ * 2048 + kk * 64);
      }
    } else {
      const float* pu = Uw + (size_t)y * DQ + lg4 * 8;
      const float* pg = Gw + (size_t)y * DQ + lg4 * 8;
      const float* pf = Fw + (size_t)y * DQ + lg4 * 8;
#pragma unroll
      for (int kk = 0; kk < 16; ++kk) {
        wU[kk] = pack8(*(const float4*)(pu + kk * 32), *(const float4*)(pu + kk * 32 + 4));
        wG[kk] = pack8(*(const float4*)(pg + kk * 32), *(const float4*)(pg + kk * 32 + 4));
        wF[kk] = pack8(*(const float4*)(pf + kk * 32), *(const float4*)(pf + kk * 32 + 4));
      }
    }
  }

  float lU = 0.f, aU = 0.f, lG = 0.f, aG = 0.f;

  if constexpr (FULL) {
    // gx quarter into LDS (keeps loop vmcnt accounting pure)
    *(float2*)(smem + GXOFF + tid * 8) = *(const float2*)(gx + b * NQ + nbase + tid * 2);
    const char* xb = ws_x2 + (((size_t)(b * 128 + nh * 32)) << 14);
    auto stage = [&](int c) {
      const char* src = xb + ((size_t)c << 14);
      char* lb = smem + (c & 3) * 16384;
#pragma unroll
      for (int j = 0; j < 4; ++j) {
        int s = w * 4 + j;
        gl_lds16(src + s * 1024 + l * 16, lb + s * 1024);
      }
    };
    auto compute = [&](int c) {
      const char* ab = smem + (c & 3) * 16384 + l * 16;
      f32x4 sU = {0.f, 0.f, 0.f, 0.f}, sG = sU, sF = sU;
      __builtin_amdgcn_s_setprio(1);
#pragma unroll
      for (int kk = 0; kk < 16; ++kk) {
        bf16x8 a = *(const bf16x8*)(ab + kk * 1024);
        sU = __builtin_amdgcn_mfma_f32_16x16x32_bf16(a, wU[kk], sU, 0, 0, 0);
        sG = __builtin_amdgcn_mfma_f32_16x16x32_bf16(a, wG[kk], sG, 0, 0, 0);
        sF = __builtin_amdgcn_mfma_f32_16x16x32_bf16(a, wF[kk], sF, 0, 0, 0);
      }
      __builtin_amdgcn_s_setprio(0);
      float4 gxv = *(const float4*)(smem + GXOFF + c * 64 + lg4 * 16);
      float gv[4] = {gxv.x, gxv.y, gxv.z, gxv.w};
#pragma unroll
      for (int r = 0; r < 4; ++r) {
        float eu = __builtin_amdgcn_exp2f(sU[r] * L2E);
        lU += eu; aU = fmaf(eu, sF[r], aU);
        float eg = __builtin_amdgcn_exp2f(sG[r] * L2E);
        lG += eg; aG = fmaf(eg, gv[r], aG);
      }
    };

    __syncthreads();                 // full drain: clean vmcnt baseline
    stage(0); stage(1);              // pending groups {0,1} (8)
    asm volatile("s_waitcnt vmcnt(4)" ::: "memory");   // chunk0 ready
    __builtin_amdgcn_s_barrier();

#pragma unroll 1
    for (int cp = 0; cp < NCHQ / 2; ++cp) {
      const int c0 = 2 * cp;
      if (cp < NCHQ / 2 - 1) { stage(c0 + 2); stage(c0 + 3); }  // pending {c0+1,c0+2,c0+3}
      compute(c0);
      if (cp < NCHQ / 2 - 1) asm volatile("s_waitcnt vmcnt(8)" ::: "memory");  // c0+1 ready
      else                   asm volatile("s_waitcnt vmcnt(0)" ::: "memory");
      compute(c0 + 1);
      if (cp < NCHQ / 2 - 1) {
        asm volatile("s_waitcnt vmcnt(4)" ::: "memory");         // c0+2 ready
        __builtin_amdgcn_sched_barrier(0);
        __builtin_amdgcn_s_barrier();
      }
    }
  } else {
    const float* gxb = gx + b * NQ + nbase + lg4 * 4;
    for (int c = 0; c < NCHQ; ++c) {
      __syncthreads();
#pragma unroll
      for (int j = 0; j < 4; ++j) {
        int slot = j * 256 + tid;                  // 1024 slots * 16B = 16KB
        int kk = slot >> 6, l2 = slot & 63;
        int row = l2 & 15, g4 = l2 >> 4;
        const float* g = x + ((size_t)(b * NQ + nbase + c * 16 + row)) * DQ
                       + kk * 32 + g4 * 8;
        *(bf16x8*)(smem + slot * 16) = pack8(*(const float4*)g, *(const float4*)(g + 4));
      }
      __syncthreads();
      const char* ab = smem + l * 16;
      f32x4 sU = {0.f, 0.f, 0.f, 0.f}, sG = sU, sF = sU;
#pragma unroll
      for (int kk = 0; kk < 16; ++kk) {
        bf16x8 a = *(const bf16x8*)(ab + kk * 1024);
        sU = __builtin_amdgcn_mfma_f32_16x16x32_bf16(a, wU[kk], sU, 0, 0, 0);
        sG = __builtin_amdgcn_mfma_f32_16x16x32_bf16(a, wG[kk], sG, 0, 0, 0);
        sF = __builtin_amdgcn_mfma_f32_16x16x32_bf16(a, wF[kk], sF, 0, 0, 0);
      }
      float4 gxv = *(const float4*)(gxb + c * 16);
      float gv[4] = {gxv.x, gxv.y, gxv.z, gxv.w};
#pragma unroll
      for (int r = 0; r < 4; ++r) {
        float eu = __builtin_amdgcn_exp2f(sU[r] * L2E);
        lU += eu; aU = fmaf(eu, sF[r], aU);
        float eg = __builtin_amdgcn_exp2f(sG[r] * L2E);
        lG += eg; aG = fmaf(eg, gv[r], aG);
      }
    }
  }

  // ---- additive lane-group merge ----
#pragma unroll
  for (int d = 16; d < 64; d <<= 1) {
    lU += __shfl_xor(lU, d); aU += __shfl_xor(aU, d);
    lG += __shfl_xor(lG, d); aG += __shfl_xor(aG, d);
  }

  int y = ybase + lr;
  if (lg4 == 0 && y < YQ) {
    float4 st; st.x = lU; st.y = aU; st.z = lG; st.w = aG;
    ws_state[(size_t)(b * NH + nh) * YQ + y] = st;
  }
}

// ---- merge quarters + epilogue + loss partials ----
__global__ __launch_bounds__(256) void merge_kernel(
    const float4* __restrict__ ws_state, const float* __restrict__ fb,
    const float* __restrict__ gate_b, const float* __restrict__ yflow,
    const float* __restrict__ target, float* __restrict__ out_y,
    float* __restrict__ loss_part) {
  __shared__ float sb[256];
  int t = blockIdx.x * 256 + threadIdx.x;
  float lt = 0.f;
  if (t < BQ * YQ) {
    int b = t / YQ, y = t % YQ;
    float lU = 0.f, aU = 0.f, lG = 0.f, aG = 0.f;
#pragma unroll
    for (int nh = 0; nh < NH; ++nh) {
      float4 s = ws_state[(size_t)(b * NH + nh) * YQ + y];
      lU += s.x; aU += s.y; lG += s.z; aG += s.w;
    }
    float gate = tanhf(aG / lG + gate_b[0]);
    float yv = aU / lU + fb[y] + yflow[t] * gate;
    out_y[t] = yv;
    float tg = target[t];
    lt = fmaxf(yv, 0.f) + log1pf(__expf(-fabsf(yv))) - yv * tg;
  }
  sb[threadIdx.x] = lt;
  __syncthreads();
  for (int st = 128; st > 0; st >>= 1) {
    if (threadIdx.x < st) sb[threadIdx.x] += sb[threadIdx.x + st];
    __syncthreads();
  }
  if (threadIdx.x == 0) loss_part[blockIdx.x] = sb[0];
}

__global__ __launch_bounds__(256) void loss_kernel(const float* __restrict__ lp,
                                                   float* __restrict__ out) {
  __shared__ float sb[256];
  float s = (threadIdx.x < NLP) ? lp[threadIdx.x] : 0.f;
  sb[threadIdx.x] = s;
  __syncthreads();
  for (int st = 128; st > 0; st >>= 1) {
    if (threadIdx.x < st) sb[threadIdx.x] += sb[threadIdx.x + st];
    __syncthreads();
  }
  if (threadIdx.x == 0) out[BQ * YQ] = sb[0] / (float)(BQ * YQ);
}

extern "C" void kernel_launch(void* const* d_in, const int* in_sizes, int n_in,
                              void* d_out, int out_size, void* d_ws, size_t ws_size,
                              hipStream_t stream) {
  const float* x      = (const float*)d_in[0];
  const float* target = (const float*)d_in[1];
  const float* yflow  = (const float*)d_in[2];
  const float* Uw     = (const float*)d_in[3];
  const float* Gw     = (const float*)d_in[4];
  const float* Fw     = (const float*)d_in[5];
  const float* fb     = (const float*)d_in[6];
  const float* gw     = (const float*)d_in[7];
  const float* gb     = (const float*)d_in[8];
  float* out = (float*)d_out;
  char* ws = (char*)d_ws;

  const size_t xbytes  = (size_t)BQ * NQ * DQ * 2;          // 8 MB frag-ordered
  const size_t wbytes  = (size_t)3 * YQ * DQ * 2;           // ~27.4 MB
  const size_t gxbytes = (size_t)BQ * NQ * 4;               // 32 KB
  const size_t stbytes = (size_t)BQ * NH * YQ * 16;         // ~2.3 MB
  const size_t lpbytes = (size_t)NLP * 4;
  const bool full = ws_size >= xbytes + wbytes + gxbytes + stbytes + lpbytes;

  char* ws_x2; char* ws_w; float* gxp; float4* stp; float* lp;
  if (full) {
    ws_x2 = ws; ws_w = ws + xbytes;
    gxp = (float*)(ws + xbytes + wbytes);
    stp = (float4*)(ws + xbytes + wbytes + gxbytes);
    lp  = (float*)(ws + xbytes + wbytes + gxbytes + stbytes);
  } else {
    ws_x2 = nullptr; ws_w = nullptr;
    gxp = (float*)ws;
    stp = (float4*)(ws + gxbytes);
    lp  = (float*)(ws + gxbytes + stbytes);
  }

  (void)hipFuncSetAttribute(reinterpret_cast<const void*>(&fused_kernel<true>),
                            hipFuncAttributeMaxDynamicSharedMemorySize, 67584);
  (void)hipFuncSetAttribute(reinterpret_cast<const void*>(&fused_kernel<false>),
                            hipFuncAttributeMaxDynamicSharedMemorySize, 16384);

  prep_gx<<<dim3(2048), 256, 0, stream>>>(x, gw, gxp);
  if (full) {
    prep_xfrag<<<dim3(BQ * 128), 256, 0, stream>>>(x, ws_x2);
    prep_w<<<dim3((3 * YQ + 3) / 4), 256, 0, stream>>>(Uw, Gw, Fw, ws_w);
    fused_kernel<true ><<<dim3(NUNITS), 256, 67584, stream>>>(
        x, ws_x2, ws_w, Uw, Gw, Fw, gxp, stp);
  } else {
    fused_kernel<false><<<dim3(NUNITS), 256, 16384, stream>>>(
        x, ws_x2, ws_w, Uw, Gw, Fw, gxp, stp);
  }
  merge_kernel<<<dim3(NLP), 256, 0, stream>>>(stp, fb, gb, yflow, target, out, lp);
  loss_kernel<<<1, 256, 0, stream>>>(lp, out);
}